// Round 1
// baseline (96.568 us; speedup 1.0000x reference)
//
#include <hip/hip_runtime.h>

#define L_SIG   48000
#define WLEN    1025
#define FPW     8                      // frames per wave
#define WPB     4                      // waves per block (256 threads)
#define NBLOCKS (L_SIG / (FPW * WPB))  // 1500

#if __has_builtin(__builtin_amdgcn_exp2f)
#define EXP2F(x) __builtin_amdgcn_exp2f(x)
#else
#define EXP2F(x) __exp2f(x)
#endif
#if __has_builtin(__builtin_amdgcn_rcpf)
#define RCPF(x) __builtin_amdgcn_rcpf(x)
#else
#define RCPF(x) (1.0f / (x))
#endif

// DPP-based wave64 sum: tmp = dpp_move(x) (0 for invalid/masked lanes), x += tmp.
template <int CTRL, int RMASK>
__device__ __forceinline__ float dpp_add(float x) {
    int t = __builtin_amdgcn_update_dpp(0, __float_as_int(x), CTRL, RMASK, 0xF, false);
    return x + __int_as_float(t);
}

// Full-wave sum, result broadcast to all lanes (total lands in lane 63, readlane out).
__device__ __forceinline__ float wave_sum_bcast(float x) {
    x = dpp_add<0x111, 0xF>(x);  // row_shr:1
    x = dpp_add<0x112, 0xF>(x);  // row_shr:2
    x = dpp_add<0x114, 0xF>(x);  // row_shr:4
    x = dpp_add<0x118, 0xF>(x);  // row_shr:8
    x = dpp_add<0x142, 0xA>(x);  // row_bcast:15 -> rows 1,3
    x = dpp_add<0x143, 0xC>(x);  // row_bcast:31 -> rows 2,3
    return __int_as_float(__builtin_amdgcn_readlane(__float_as_int(x), 63));
}

__global__ __launch_bounds__(256) void soft_edp_loss_kernel(
    const float* __restrict__ xp, const float* __restrict__ xt,
    const float* __restrict__ win, float* __restrict__ out) {
    const int lane = threadIdx.x & 63;
    const int wid  = blockIdx.x * WPB + (threadIdx.x >> 6);
    const int l0   = wid * FPW;

    // Window into registers: wreg[k] = win[lane + 64k] (tail masked; win[1024] only lane 0)
    float wreg[17];
#pragma unroll
    for (int k = 0; k < 16; ++k) wreg[k] = win[lane + 64 * k];
    wreg[16] = (lane == 0) ? win[1024] : 0.0f;

    const float LOG2E = 1.4426950408889634f;
    float lacc = 0.0f;

    for (int f = 0; f < FPW; ++f) {
        const int l = l0 + f;

        // ---- pass 1: load frame (both signals) into regs, accumulate sum / sumsq
        float vp[17], vt[17];
        if (l >= WLEN) {  // wave-uniform: no padding needed
            const float* xpb = xp + (l - WLEN) + lane;
            const float* xtb = xt + (l - WLEN) + lane;
#pragma unroll
            for (int k = 0; k < 16; ++k) {
                vp[k] = xpb[64 * k];
                vt[k] = xtb[64 * k];
            }
            vp[16] = (lane == 0) ? xpb[1024] : 0.0f;
            vt[16] = (lane == 0) ? xtb[1024] : 0.0f;
        } else {          // left edge: elements with negative index are zeros
#pragma unroll
            for (int k = 0; k < 16; ++k) {
                int g = (l - WLEN) + lane + 64 * k;
                vp[k] = (g >= 0) ? xp[g] : 0.0f;
                vt[k] = (g >= 0) ? xt[g] : 0.0f;
            }
            int g16 = l - 1;  // j = 1024 -> x[l-1], lane 0 only
            bool ok = (lane == 0) && (g16 >= 0);
            vp[16] = ok ? xp[g16] : 0.0f;
            vt[16] = ok ? xt[g16] : 0.0f;
        }

        float sp = 0.0f, ssp = 0.0f, st = 0.0f, sst = 0.0f;
#pragma unroll
        for (int k = 0; k < 17; ++k) {
            sp += vp[k]; ssp = fmaf(vp[k], vp[k], ssp);
            st += vt[k]; sst = fmaf(vt[k], vt[k], sst);
        }
        sp  = wave_sum_bcast(sp);
        ssp = wave_sum_bcast(ssp);
        st  = wave_sum_bcast(st);
        sst = wave_sum_bcast(sst);

        // sample std, ddof = 1
        float varp = (ssp - sp * sp * (1.0f / WLEN)) * (1.0f / (WLEN - 1));
        float vart = (sst - st * st * (1.0f / WLEN)) * (1.0f / (WLEN - 1));
        float stdp = sqrtf(fmaxf(varp, 0.0f));
        float stdt = sqrtf(fmaxf(vart, 0.0f));

        // sigmoid(|v|*kappa - std) = rcp(1 + exp2(|v|*(-kappa*log2e) + std*log2e))
        float kappa = (float)(100.0 + (99900.0 / 48000.0) * (double)l);
        float k2 = -kappa * LOG2E;
        float cp = stdp * LOG2E;
        float ct = stdt * LOG2E;

        float Sp = 0.0f, St = 0.0f;
#pragma unroll
        for (int k = 0; k < 17; ++k) {
            float ap = fmaf(fabsf(vp[k]), k2, cp);
            float ep = EXP2F(ap);
            Sp = fmaf(RCPF(1.0f + ep), wreg[k], Sp);
            float at = fmaf(fabsf(vt[k]), k2, ct);
            float et = EXP2F(at);
            St = fmaf(RCPF(1.0f + et), wreg[k], St);
        }
        Sp = wave_sum_bcast(Sp);
        St = wave_sum_bcast(St);

        float d = Sp - St;
        lacc = fmaf(d, d, lacc);
    }

    if (lane == 0) {
        // loss = sum(d^2) / (L * erfc(1/sqrt(2))^2)
        const float scale =
            (float)(1.0 / (48000.0 * 0.3173105078629141 * 0.3173105078629141));
        atomicAdd(out, lacc * scale);
    }
}

extern "C" void kernel_launch(void* const* d_in, const int* in_sizes, int n_in,
                              void* d_out, int out_size, void* d_ws, size_t ws_size,
                              hipStream_t stream) {
    const float* xp  = (const float*)d_in[0];  // y_pred, 48000 f32
    const float* xt  = (const float*)d_in[1];  // y_true, 48000 f32
    const float* win = (const float*)d_in[2];  // window, 1025 f32
    float* out = (float*)d_out;                // scalar f32

    hipMemsetAsync(out, 0, sizeof(float), stream);
    soft_edp_loss_kernel<<<NBLOCKS, WPB * 64, 0, stream>>>(xp, xt, win, out);
}

// Round 2
// 46.730 us; speedup vs baseline: 2.0665x; 2.0665x over previous
//
#include <hip/hip_runtime.h>

#define L_SIG 48000
#define WLEN  1025
#define FB    64                 // frames per block (one per lane)
#define SEGN  1092               // FB + WLEN - 1 = 1088, padded for scan edge reads
#define NBLK  (L_SIG / FB)       // 750 blocks

#if __has_builtin(__builtin_amdgcn_exp2f)
#define EXP2F(x) __builtin_amdgcn_exp2f(x)
#else
#define EXP2F(x) __exp2f(x)
#endif
#if __has_builtin(__builtin_amdgcn_rcpf)
#define RCPF(x) __builtin_amdgcn_rcpf(x)
#else
#define RCPF(x) (1.0f / (x))
#endif

// DPP add step: invalid/masked source lanes contribute 0 (old = 0, bound_ctrl off).
template <int CTRL, int RMASK>
__device__ __forceinline__ float dpp_add(float x) {
    int t = __builtin_amdgcn_update_dpp(0, __float_as_int(x), CTRL, RMASK, 0xF, false);
    return x + __int_as_float(t);
}
// 64-lane inclusive prefix sum (row_shr 1/2/4/8, then row_bcast 15 -> rows 1,3, bcast 31 -> rows 2,3)
__device__ __forceinline__ float wave_scan_incl(float x) {
    x = dpp_add<0x111, 0xF>(x);
    x = dpp_add<0x112, 0xF>(x);
    x = dpp_add<0x114, 0xF>(x);
    x = dpp_add<0x118, 0xF>(x);
    x = dpp_add<0x142, 0xA>(x);
    x = dpp_add<0x143, 0xC>(x);
    return x;
}
__device__ __forceinline__ float wave_sum_bcast(float x) {
    return __int_as_float(__builtin_amdgcn_readlane(
        __float_as_int(wave_scan_incl(x)), 63));
}

__global__ __launch_bounds__(256) void soft_edp_kernel(
    const float* __restrict__ xp, const float* __restrict__ xt,
    const float* __restrict__ win, float* __restrict__ out)
{
    __shared__ float segp[SEGN], segt[SEGN];
    __shared__ float redv[4][4];
    __shared__ float kl2s[FB], cps[FB], cts[FB];
    __shared__ float partp[4][FB], partt[4][FB];

    const int tid  = threadIdx.x;
    const int lane = tid & 63;
    const int wv   = tid >> 6;
    const int l0   = blockIdx.x * FB;
    const int g0   = l0 - WLEN;        // seg[j] = x[g0 + j], zeros outside [0, L)

    for (int j = tid; j < SEGN; j += 256) {
        int g = g0 + j;
        bool ok = (g >= 0) && (g < L_SIG);
        segp[j] = ok ? xp[g] : 0.0f;
        segt[j] = ok ? xt[g] : 0.0f;
    }
    __syncthreads();

    // ---- base sums over frame 0's window: seg[0..1024] (all 256 threads)
    float bsp = 0.f, bssp = 0.f, bst = 0.f, bsst = 0.f;
    for (int j = tid; j < WLEN; j += 256) {
        float a = segp[j], b = segt[j];
        bsp += a; bssp = fmaf(a, a, bssp);
        bst += b; bsst = fmaf(b, b, bsst);
    }
    bsp  = wave_sum_bcast(bsp);
    bssp = wave_sum_bcast(bssp);
    bst  = wave_sum_bcast(bst);
    bsst = wave_sum_bcast(bsst);
    if (lane == 0) {
        redv[wv][0] = bsp; redv[wv][1] = bssp;
        redv[wv][2] = bst; redv[wv][3] = bsst;
    }
    __syncthreads();

    // ---- wave 0: sliding-window scan -> per-frame std; stash sigmoid constants
    if (wv == 0) {
        float base_sp  = redv[0][0] + redv[1][0] + redv[2][0] + redv[3][0];
        float base_ssp = redv[0][1] + redv[1][1] + redv[2][1] + redv[3][1];
        float base_st  = redv[0][2] + redv[1][2] + redv[2][2] + redv[3][2];
        float base_sst = redv[0][3] + redv[1][3] + redv[2][3] + redv[3][3];

        // frame i sum = base + sum_{j<i} (seg[WLEN+j] - seg[j])  (exclusive scan)
        float p0 = segp[lane], p1 = segp[lane + WLEN];
        float t0 = segt[lane], t1 = segt[lane + WLEN];
        float dsp  = p1 - p0;
        float dssp = fmaf(p1, p1, -(p0 * p0));
        float dst_ = t1 - t0;
        float dsst = fmaf(t1, t1, -(t0 * t0));

        float esp  = wave_scan_incl(dsp)  - dsp;
        float essp = wave_scan_incl(dssp) - dssp;
        float est_ = wave_scan_incl(dst_) - dst_;
        float esst = wave_scan_incl(dsst) - dsst;

        float sum_p = base_sp + esp,  ss_p = base_ssp + essp;
        float sum_t = base_st + est_, ss_t = base_sst + esst;
        float varp = (ss_p - sum_p * sum_p * (1.0f / WLEN)) * (1.0f / (WLEN - 1));
        float vart = (ss_t - sum_t * sum_t * (1.0f / WLEN)) * (1.0f / (WLEN - 1));
        float stdp = sqrtf(fmaxf(varp, 0.f));
        float stdt = sqrtf(fmaxf(vart, 0.f));

        const float LOG2E = 1.4426950408889634f;
        float kappa = 100.0f + (99900.0f / 48000.0f) * (float)(l0 + lane);
        kl2s[lane] = kappa * LOG2E;
        cps[lane]  = stdp * LOG2E;
        cts[lane]  = stdt * LOG2E;
    }
    __syncthreads();

    // ---- hot loop: thread = (frame = lane, k-quarter = wave); no cross-lane ops
    const float kl2 = kl2s[lane];
    const float cp  = cps[lane];
    const float ct  = cts[lane];

    const int k0   = wv * 256;
    const int kend = (wv == 3) ? WLEN : (k0 + 256);

    float Sp = 0.f, St = 0.f, wacc = 0.f;
#pragma unroll 4
    for (int k = k0; k < kend; ++k) {
        float wk = win[k];                 // wave-uniform -> scalar load
        float vp = segp[lane + k];         // stride-1 across lanes: conflict-free
        float vt = segt[lane + k];
        // sigmoid(|v|k - std) = 1 / (1 + 2^a),  a = (std - |v|k)*log2e
        float ap = fmaf(-fabsf(vp), kl2, cp);
        float at = fmaf(-fabsf(vt), kl2, ct);
        if (__any((ap >= -24.f) || (at >= -24.f))) {
            float ep = EXP2F(ap);
            Sp = fmaf(RCPF(1.f + ep), wk, Sp);
            float et = EXP2F(at);
            St = fmaf(RCPF(1.f + et), wk, St);
        } else {
            wacc += wk;                    // both sigmoids == 1 to < 2^-24
        }
    }
    Sp += wacc;
    St += wacc;
    partp[wv][lane] = Sp;
    partt[wv][lane] = St;
    __syncthreads();

    // ---- combine k-quarters, square differences, one atomic per block
    if (wv == 0) {
        float SP = partp[0][lane] + partp[1][lane] + partp[2][lane] + partp[3][lane];
        float ST = partt[0][lane] + partt[1][lane] + partt[2][lane] + partt[3][lane];
        float d  = SP - ST;
        float dd = wave_sum_bcast(d * d);
        if (lane == 0) {
            const float scale =
                (float)(1.0 / (48000.0 * 0.3173105078629141 * 0.3173105078629141));
            atomicAdd(out, dd * scale);
        }
    }
}

extern "C" void kernel_launch(void* const* d_in, const int* in_sizes, int n_in,
                              void* d_out, int out_size, void* d_ws, size_t ws_size,
                              hipStream_t stream) {
    const float* xp  = (const float*)d_in[0];  // y_pred, 48000 f32
    const float* xt  = (const float*)d_in[1];  // y_true, 48000 f32
    const float* win = (const float*)d_in[2];  // window, 1025 f32
    float* out = (float*)d_out;

    hipMemsetAsync(out, 0, sizeof(float), stream);
    soft_edp_kernel<<<NBLK, 256, 0, stream>>>(xp, xt, win, out);
}

// Round 4
// 27.557 us; speedup vs baseline: 3.5043x; 1.6958x over previous
//
#include <hip/hip_runtime.h>

#define L_SIG  48000
#define WLEN   1025
#define FB     64                  // frames per block (one per lane)
#define WAVES  8
#define THREADS (WAVES * 64)       // 512
#define KSLICE 128                 // k-taps per wave (8*128 = 1024; tap 1024 peeled)
#define SEGN   1092                // FB + WLEN = 1089, padded
#define NBLK   (L_SIG / FB)        // 750

#if __has_builtin(__builtin_amdgcn_exp2f)
#define EXP2F(x) __builtin_amdgcn_exp2f(x)
#else
#define EXP2F(x) __exp2f(x)
#endif
#if __has_builtin(__builtin_amdgcn_rcpf)
#define RCPF(x) __builtin_amdgcn_rcpf(x)
#else
#define RCPF(x) (1.0f / (x))
#endif

// DPP add step: invalid/masked source lanes contribute 0 (old = 0, bound_ctrl off).
template <int CTRL, int RMASK>
__device__ __forceinline__ float dpp_add(float x) {
    int t = __builtin_amdgcn_update_dpp(0, __float_as_int(x), CTRL, RMASK, 0xF, false);
    return x + __int_as_float(t);
}
// 64-lane inclusive prefix sum
__device__ __forceinline__ float wave_scan_incl(float x) {
    x = dpp_add<0x111, 0xF>(x);  // row_shr:1
    x = dpp_add<0x112, 0xF>(x);  // row_shr:2
    x = dpp_add<0x114, 0xF>(x);  // row_shr:4
    x = dpp_add<0x118, 0xF>(x);  // row_shr:8
    x = dpp_add<0x142, 0xA>(x);  // row_bcast:15 -> rows 1,3
    x = dpp_add<0x143, 0xC>(x);  // row_bcast:31 -> rows 2,3
    return x;
}
__device__ __forceinline__ float wave_sum_bcast(float x) {
    return __int_as_float(__builtin_amdgcn_readlane(
        __float_as_int(wave_scan_incl(x)), 63));
}

__global__ __launch_bounds__(THREADS) void soft_edp_kernel(
    const float* __restrict__ xp, const float* __restrict__ xt,
    const float* __restrict__ win, float* __restrict__ out)
{
    __shared__ float segp[SEGN], segt[SEGN];
    __shared__ float redv[WAVES][4];
    __shared__ float kl2s[FB], cps[FB], cts[FB];
    __shared__ float partp[WAVES][FB], partt[WAVES][FB];

    const int tid  = threadIdx.x;
    const int lane = tid & 63;
    const int wv   = tid >> 6;
    const int l0   = blockIdx.x * FB;
    const int g0   = l0 - WLEN;        // seg[j] = x[g0 + j], zeros outside [0, L)

    for (int j = tid; j < SEGN; j += THREADS) {
        int g = g0 + j;
        bool ok = (g >= 0) && (g < L_SIG);
        segp[j] = ok ? xp[g] : 0.0f;
        segt[j] = ok ? xt[g] : 0.0f;
    }
    __syncthreads();

    // ---- base sums over frame 0's window: seg[0..1024] (all threads)
    float bsp = 0.f, bssp = 0.f, bst = 0.f, bsst = 0.f;
    for (int j = tid; j < WLEN; j += THREADS) {
        float a = segp[j], b = segt[j];
        bsp += a; bssp = fmaf(a, a, bssp);
        bst += b; bsst = fmaf(b, b, bsst);
    }
    bsp  = wave_sum_bcast(bsp);
    bssp = wave_sum_bcast(bssp);
    bst  = wave_sum_bcast(bst);
    bsst = wave_sum_bcast(bsst);
    if (lane == 0) {
        redv[wv][0] = bsp; redv[wv][1] = bssp;
        redv[wv][2] = bst; redv[wv][3] = bsst;
    }
    __syncthreads();

    // ---- wave 0: sliding-window scan -> per-frame std; stash sigmoid constants
    if (wv == 0) {
        float base_sp = 0.f, base_ssp = 0.f, base_st = 0.f, base_sst = 0.f;
#pragma unroll
        for (int w = 0; w < WAVES; ++w) {
            base_sp  += redv[w][0]; base_ssp += redv[w][1];
            base_st  += redv[w][2]; base_sst += redv[w][3];
        }
        // frame i sum = base + sum_{j<i} (seg[WLEN+j] - seg[j])  (exclusive scan)
        float p0 = segp[lane], p1 = segp[lane + WLEN];
        float t0 = segt[lane], t1 = segt[lane + WLEN];
        float dsp  = p1 - p0;
        float dssp = fmaf(p1, p1, -(p0 * p0));
        float dst_ = t1 - t0;
        float dsst = fmaf(t1, t1, -(t0 * t0));

        float esp  = wave_scan_incl(dsp)  - dsp;
        float essp = wave_scan_incl(dssp) - dssp;
        float est_ = wave_scan_incl(dst_) - dst_;
        float esst = wave_scan_incl(dsst) - dsst;

        float sum_p = base_sp + esp,  ss_p = base_ssp + essp;
        float sum_t = base_st + est_, ss_t = base_sst + esst;
        float varp = (ss_p - sum_p * sum_p * (1.0f / WLEN)) * (1.0f / (WLEN - 1));
        float vart = (ss_t - sum_t * sum_t * (1.0f / WLEN)) * (1.0f / (WLEN - 1));
        float stdp = sqrtf(fmaxf(varp, 0.f));
        float stdt = sqrtf(fmaxf(vart, 0.f));

        const float LOG2E = 1.4426950408889634f;
        float kappa = 100.0f + (99900.0f / 48000.0f) * (float)(l0 + lane);
        kl2s[lane] = kappa * LOG2E;
        cps[lane]  = stdp * LOG2E;
        cts[lane]  = stdt * LOG2E;
    }
    __syncthreads();

    // ---- hot loop: thread = (frame = lane, k-slice = wave); no cross-lane ops
    const float kl2 = kl2s[lane];
    const float cp  = cps[lane];
    const float ct  = cts[lane];

    // uniform k base (readfirstlane forces SGPR -> win[] becomes s_load)
    const int k0u = __builtin_amdgcn_readfirstlane(wv * KSLICE);

    float Sp = 0.f, St = 0.f, wacc = 0.f;
#pragma unroll 4
    for (int i = 0; i < KSLICE; i += 2) {
        const int k = k0u + i;             // wave-uniform scalar
        const int idx = lane + k;
        float pa = segp[idx], pb = segp[idx + 1];   // merge -> ds_read2_b32
        float ta = segt[idx], tb = segt[idx + 1];
        float wk0 = win[k], wk1 = win[k + 1];       // uniform -> s_load

        // a = (std - |v|*kappa)*log2e ; sigmoid = 1/(1+2^a)
        float a0 = fmaf(-fabsf(pa), kl2, cp);
        float b0 = fmaf(-fabsf(ta), kl2, ct);
        float a1 = fmaf(-fabsf(pb), kl2, cp);
        float b1 = fmaf(-fabsf(tb), kl2, ct);
        float m  = fmaxf(fmaxf(a0, b0), fmaxf(a1, b1));
        if (__any(m >= -24.f)) {
            float e0 = EXP2F(a0);
            Sp = fmaf(RCPF(1.f + e0), wk0, Sp);
            float e1 = EXP2F(a1);
            Sp = fmaf(RCPF(1.f + e1), wk1, Sp);
            float f0 = EXP2F(b0);
            St = fmaf(RCPF(1.f + f0), wk0, St);
            float f1 = EXP2F(b1);
            St = fmaf(RCPF(1.f + f1), wk1, St);
        } else {
            wacc += (wk0 + wk1);           // both sigmoids == 1 to < 2^-24
        }
    }
    Sp += wacc;
    St += wacc;

    // peeled final tap k = 1024 (wave 0 only)
    if (wv == 0) {
        float wk = win[1024];
        float p = segp[lane + 1024], t = segt[lane + 1024];
        float a = fmaf(-fabsf(p), kl2, cp);
        float b = fmaf(-fabsf(t), kl2, ct);
        Sp = fmaf(RCPF(1.f + EXP2F(a)), wk, Sp);
        St = fmaf(RCPF(1.f + EXP2F(b)), wk, St);
    }

    partp[wv][lane] = Sp;
    partt[wv][lane] = St;
    __syncthreads();

    // ---- combine k-slices, square differences, one atomic per block
    if (wv == 0) {
        float SP = 0.f, ST = 0.f;
#pragma unroll
        for (int w = 0; w < WAVES; ++w) {
            SP += partp[w][lane];
            ST += partt[w][lane];
        }
        float d  = SP - ST;
        float dd = wave_sum_bcast(d * d);
        if (lane == 0) {
            const float scale =
                (float)(1.0 / (48000.0 * 0.3173105078629141 * 0.3173105078629141));
            atomicAdd(out, dd * scale);
        }
    }
}

extern "C" void kernel_launch(void* const* d_in, const int* in_sizes, int n_in,
                              void* d_out, int out_size, void* d_ws, size_t ws_size,
                              hipStream_t stream) {
    const float* xp  = (const float*)d_in[0];  // y_pred, 48000 f32
    const float* xt  = (const float*)d_in[1];  // y_true, 48000 f32
    const float* win = (const float*)d_in[2];  // window, 1025 f32
    float* out = (float*)d_out;

    hipMemsetAsync(out, 0, sizeof(float), stream);
    soft_edp_kernel<<<NBLK, THREADS, 0, stream>>>(xp, xt, win, out);
}